// Round 6
// baseline (494.063 us; speedup 1.0000x reference)
//
#include <hip/hip_runtime.h>
#include <math.h>

#define HS 4096
#define NIN 17
#define ROW_CHUNKS 512
#define ROWS_PER_CHUNK (HS / ROW_CHUNKS)   // 8

typedef float vfloat4 __attribute__((ext_vector_type(4)));

// Kernel 1: matvec partials of hidden @ (w + alpha*hebb). Pure 3-stream read.
// grid (4, 512) x 256. launch_bounds(256,4) -> VGPR cap 128 so all 24 float4
// loads can be in flight before the FMA chain (MLP was the round-4 limiter:
// VGPR_Count=32 allowed only ~5 outstanding loads -> 2.6 TB/s).
__global__ __launch_bounds__(256, 4) void matvec_k(
    const float* __restrict__ hidden, const float* __restrict__ w,
    const float* __restrict__ alpha, const float* __restrict__ hebb,
    float* __restrict__ partial) {
  const int j4 = blockIdx.x * blockDim.x + threadIdx.x;   // float4 col idx, 0..1023
  const int row0 = blockIdx.y * ROWS_PER_CHUNK;
  const size_t base = (size_t)row0 * (HS / 4) + j4;
  const vfloat4* wp = reinterpret_cast<const vfloat4*>(w) + base;
  const vfloat4* ap = reinterpret_cast<const vfloat4*>(alpha) + base;
  const vfloat4* bp = reinterpret_cast<const vfloat4*>(hebb) + base;

  vfloat4 wv[ROWS_PER_CHUNK], av[ROWS_PER_CHUNK], bv[ROWS_PER_CHUNK];
#pragma unroll
  for (int r = 0; r < ROWS_PER_CHUNK; ++r) {
    wv[r] = wp[(size_t)r * (HS / 4)];
    av[r] = ap[(size_t)r * (HS / 4)];
    bv[r] = bp[(size_t)r * (HS / 4)];
  }
  vfloat4 acc = (vfloat4)(0.f);
#pragma unroll
  for (int r = 0; r < ROWS_PER_CHUNK; ++r) {
    const float h = hidden[row0 + r];   // wave-uniform -> scalar load
#pragma unroll
    for (int c = 0; c < 4; ++c)
      acc[c] = fmaf(h, fmaf(av[r][c], bv[r][c], wv[r][c]), acc[c]);
  }
  reinterpret_cast<vfloat4*>(partial)[(size_t)blockIdx.y * (HS / 4) + j4] = acc;
}

// Kernel 2: one wave per column. Reduce 512 partials + i2h + bias, tanh.
__global__ __launch_bounds__(64) void finalize_k(
    const float* __restrict__ partial, const float* __restrict__ inputs,
    const float* __restrict__ i2h_w, const float* __restrict__ i2h_b,
    float* __restrict__ out_hactiv) {
  const int j = blockIdx.x;
  const int lane = threadIdx.x;
  float s = 0.f;
#pragma unroll
  for (int i = 0; i < ROW_CHUNKS / 64; ++i)
    s += partial[(size_t)(lane + 64 * i) * HS + j];
  if (lane < NIN) s = fmaf(inputs[lane], i2h_w[j * NIN + lane], s);
#pragma unroll
  for (int off = 32; off > 0; off >>= 1) s += __shfl_down(s, off, 64);
  if (lane == 0) out_hactiv[j] = tanhf(s + i2h_b[j]);
}

// Kernel 3: 5 dot products (4 action head rows + value head).
__global__ __launch_bounds__(256) void heads_k(
    const float* __restrict__ hactiv, const float* __restrict__ h2o_w,
    const float* __restrict__ h2o_b, const float* __restrict__ h2v_w,
    const float* __restrict__ h2v_b, float* __restrict__ out) {
  const int r = blockIdx.x;
  const float* wrow = (r < 4) ? (h2o_w + (size_t)r * HS) : h2v_w;
  float s = 0.f;
  for (int j = threadIdx.x; j < HS; j += 256) s = fmaf(hactiv[j], wrow[j], s);
  __shared__ float red[256];
  red[threadIdx.x] = s;
  __syncthreads();
  for (int off = 128; off > 0; off >>= 1) {
    if (threadIdx.x < off) red[threadIdx.x] += red[threadIdx.x + off];
    __syncthreads();
  }
  if (threadIdx.x == 0) out[r] = red[0] + ((r < 4) ? h2o_b[r] : h2v_b[0]);
}

// Kernel 4: fused elementwise — hebb update + et/pw pass-through.
// Fill-kernel shape: 2^21 threads, 8 fully-unrolled grid-stride iterations
// (8 independent dword load/stores in flight), wave-contiguous dwords
// (dst offset 4101 floats is only 4B-aligned). hebb read is L3-warm from K1.
#define EW_THREADS (1u << 21)                 // 8192 blocks x 256
__global__ __launch_bounds__(256) void elementwise_k(
    const float* __restrict__ hebb, const float* __restrict__ hidden,
    const float* __restrict__ hactiv, const float* __restrict__ eta,
    const float* __restrict__ et, const float* __restrict__ pw,
    float* __restrict__ out_hebb, float* __restrict__ out_et,
    float* __restrict__ out_pw) {
  const unsigned tid = blockIdx.x * blockDim.x + threadIdx.x;
  const float e = eta[0];
  const float ome = 1.f - e;
#pragma unroll
  for (int i = 0; i < 8; ++i) {   // 2^24 / 2^21
    const unsigned t = tid + (unsigned)i * EW_THREADS;
    const float hi = hidden[t >> 12];        // wave-uniform
    const float ha = hactiv[t & (HS - 1)];   // L1-resident
    out_hebb[t] = fmaf(ome, hebb[t], e * hi * ha);
  }
#pragma unroll
  for (int i = 0; i < 8; ++i) {
    const unsigned t = tid + (unsigned)i * EW_THREADS;
    out_et[t] = et[t];
  }
#pragma unroll
  for (int i = 0; i < 8; ++i) {
    const unsigned t = tid + (unsigned)i * EW_THREADS;
    out_pw[t] = pw[t];
  }
}

extern "C" void kernel_launch(void* const* d_in, const int* in_sizes, int n_in,
                              void* d_out, int out_size, void* d_ws, size_t ws_size,
                              hipStream_t stream) {
  const float* inputs = (const float*)d_in[0];
  const float* hidden = (const float*)d_in[1];
  const float* hebb   = (const float*)d_in[2];
  const float* et     = (const float*)d_in[3];
  const float* pw     = (const float*)d_in[4];
  const float* i2h_w  = (const float*)d_in[5];
  const float* i2h_b  = (const float*)d_in[6];
  const float* w      = (const float*)d_in[7];
  const float* alpha  = (const float*)d_in[8];
  const float* eta    = (const float*)d_in[9];
  const float* h2o_w  = (const float*)d_in[10];
  const float* h2o_b  = (const float*)d_in[11];
  const float* h2v_w  = (const float*)d_in[12];
  const float* h2v_b  = (const float*)d_in[13];

  float* out = (float*)d_out;
  const size_t NSQ = (size_t)HS * HS;
  float* out_heads  = out;               // activout[4] + valueout[1]
  float* out_hactiv = out + 5;           // [HS]
  float* out_hebb   = out + 5 + HS;      // [HS*HS] (float offset 4101)
  float* out_et     = out_hebb + NSQ;
  float* out_pw     = out_et + NSQ;

  // Partial scratch: 512*4096 floats = 8 MB. Prefer d_ws; else an aligned
  // slice of the hebb output region (consumed before elementwise_k overwrites).
  const size_t need = (size_t)ROW_CHUNKS * HS * sizeof(float);
  float* partial = (ws_size >= need) ? (float*)d_ws
                                     : (out_hebb + 3 /* float off 4104, 16B-aligned */);

  hipLaunchKernelGGL(matvec_k, dim3(HS / 4 / 256, ROW_CHUNKS), dim3(256),
                     0, stream, hidden, w, alpha, hebb, partial);
  hipLaunchKernelGGL(finalize_k, dim3(HS), dim3(64), 0, stream,
                     partial, inputs, i2h_w, i2h_b, out_hactiv);
  hipLaunchKernelGGL(heads_k, dim3(5), dim3(256), 0, stream,
                     out_hactiv, h2o_w, h2o_b, h2v_w, h2v_b, out_heads);
  hipLaunchKernelGGL(elementwise_k, dim3(EW_THREADS / 256), dim3(256), 0, stream,
                     hebb, hidden, out_hactiv, eta, et, pw,
                     out_hebb, out_et, out_pw);
}